// Round 14
// baseline (280.903 us; speedup 1.0000x reference)
//
#include <hip/hip_runtime.h>

typedef __attribute__((ext_vector_type(8))) short short8;
typedef __attribute__((ext_vector_type(4))) float f32x4;
typedef __attribute__((ext_vector_type(2))) unsigned int u32x2;
typedef __attribute__((ext_vector_type(4))) unsigned int u32x4;

__device__ __forceinline__ unsigned short f2bf(float f) {
  unsigned u = __float_as_uint(f);
  u += 0x7FFF + ((u >> 16) & 1);   // RNE to bf16
  return (unsigned short)(u >> 16);
}
__device__ __forceinline__ unsigned packbf(float a, float b) {
  return (unsigned)f2bf(a) | ((unsigned)f2bf(b) << 16);
}
__device__ __forceinline__ float bf2f(unsigned short s) {
  return __uint_as_float(((unsigned)s) << 16);
}
__device__ __forceinline__ f32x4 mfma16(short8 a, short8 b, f32x4 c) {
  return __builtin_amdgcn_mfma_f32_16x16x32_bf16(a, b, c, 0, 0, 0);
}

typedef __attribute__((address_space(3))) unsigned int lds_u32;
typedef __attribute__((address_space(1))) const unsigned int glb_u32;
__device__ __forceinline__ void gll16(const void* g, void* l) {
  // dest = wave-uniform LDS base; HW adds lane*16 (m104). size literal 16.
  __builtin_amdgcn_global_load_lds((glb_u32*)g, (lds_u32*)l, 16, 0, 0);
}

// ---------------- converts ----------------
// vectorized: 4 f32 in, 4 bf16 out per thread (G13)
__global__ void cvt_x_kernel(const float* __restrict__ in, unsigned short* __restrict__ out, int n4) {
  int i = blockIdx.x * 256 + threadIdx.x;
  if (i < n4) {
    float4 v = ((const float4*)in)[i];
    u32x2 w;
    w.x = packbf(v.x, v.y);
    w.y = packbf(v.z, v.w);
    *(u32x2*)(out + i * 4) = w;
  }
}

// ---- fused coalesced transpose of all 4 weight matrices (LDS 32x32 tile) ----
__global__ void transpose4_kernel(const float* __restrict__ Qw, const float* __restrict__ Kw,
                                  const float* __restrict__ Vw, const float* __restrict__ Pw,
                                  unsigned short* __restrict__ WqT, unsigned short* __restrict__ WkT,
                                  unsigned short* __restrict__ WvT, unsigned short* __restrict__ PwT) {
  __shared__ float tile[32][33];           // +1 pad: transposed reads conflict-free
  const int z = blockIdx.z;
  const float* src;
  unsigned short* dst;
  int K, N, kt, nt;
  if (z < 3) {
    src = (z == 0) ? Qw : (z == 1) ? Kw : Vw;
    dst = (z == 0) ? WqT : (z == 1) ? WkT : WvT;
    K = 256; N = 2048;
    nt = blockIdx.x; kt = blockIdx.y;      // 64 x 8 tiles
  } else {
    src = Pw; dst = PwT;
    K = 2048; N = 256;
    kt = blockIdx.x; nt = blockIdx.y;      // 64 x 8 tiles
  }
  const int tx = threadIdx.x & 31, ty = threadIdx.x >> 5;
  const int k0 = kt * 32, n0 = nt * 32;
#pragma unroll
  for (int j = 0; j < 4; ++j)              // coalesced 128B row reads
    tile[ty + j * 8][tx] = src[(size_t)(k0 + ty + j * 8) * N + n0 + tx];
  __syncthreads();
#pragma unroll
  for (int j = 0; j < 4; ++j)              // coalesced 64B row writes, out[n][k] = in[k][n]
    dst[(size_t)(n0 + ty + j * 8) * K + k0 + tx] = f2bf(tile[tx][ty + j * 8]);
}

// ---------------- GEMM: C[M,N] = A[M,K] @ BT[N,K]^T + bias, BK=64 ----------------
// Half the barrier-drains of the BK=32 version. LDS rows are 128B (8 chunks of
// 16B); chunk placement XOR-swizzled by (row&7) on BOTH sides (rule 21):
// staging source pre-permuted within each row (keeps 128B-line coalescing),
// fragment reads apply ^(row&7) -> 2-way bank access = free (m136).
template<int MODE, int BMI>
__global__ __launch_bounds__(256, 2) void gemm128(const unsigned short* __restrict__ A,
    const unsigned short* __restrict__ BT, const float* __restrict__ bias,
    void* __restrict__ Cout, int Mdim, int Ndim, int Kdim) {
  constexpr int BM = 64 * BMI, MI = 2 * BMI;
  __shared__ __align__(16) short As[BM * 64];
  __shared__ __align__(16) short Bs[128 * 64];
  const int tid = threadIdx.x;
  const int wid = tid >> 6, lane = tid & 63;
  const int l15 = lane & 15, lg = lane >> 4;
  const int m0 = blockIdx.y * BM, n0 = blockIdx.x * 128;
  const int wr = (wid >> 1) * (BM / 2), wc = (wid & 1) * 64;
  const int srow = lane >> 3;                           // 8 rows per gll16 (128B rows)
  const int sx = ((lane & 7) ^ (lane >> 3)) * 8;        // pre-swizzled source chunk
  const f32x4 z = {0.f, 0.f, 0.f, 0.f};
  f32x4 acc[MI][4];
#pragma unroll
  for (int mi = 0; mi < MI; ++mi)
#pragma unroll
    for (int ni = 0; ni < 4; ++ni) acc[mi][ni] = z;

  for (int kt = 0; kt < Kdim; kt += 64) {
#pragma unroll
    for (int i = 0; i < 2 * BMI; ++i) {    // A: BM rows x 128B, 8 rows per gll16
      int r0 = wid * (BM / 4) + i * 8;
      gll16(A + (size_t)(m0 + r0 + srow) * Kdim + kt + sx, &As[r0 * 64]);
    }
#pragma unroll
    for (int i = 0; i < 4; ++i) {          // B: 128 rows x 128B
      int r0 = wid * 32 + i * 8;
      gll16(BT + (size_t)(n0 + r0 + srow) * Kdim + kt + sx, &Bs[r0 * 64]);
    }
    __syncthreads();                       // drains vmcnt (m97 pattern), now 1/2 as often
#pragma unroll
    for (int ks = 0; ks < 2; ++ks) {
      short8 a[MI], b[4];
#pragma unroll
      for (int mi = 0; mi < MI; ++mi) {
        int row = wr + mi * 16 + l15;
        a[mi] = *(const short8*)&As[row * 64 + (((ks * 4 + lg) ^ (row & 7)) * 8)];
      }
#pragma unroll
      for (int ni = 0; ni < 4; ++ni) {
        int row = wc + ni * 16 + l15;
        b[ni] = *(const short8*)&Bs[row * 64 + (((ks * 4 + lg) ^ (row & 7)) * 8)];
      }
#pragma unroll
      for (int mi = 0; mi < MI; ++mi)
#pragma unroll
        for (int ni = 0; ni < 4; ++ni)
          acc[mi][ni] = mfma16(a[mi], b[ni], acc[mi][ni]);
    }
    __syncthreads();
  }
#pragma unroll
  for (int mi = 0; mi < MI; ++mi)
#pragma unroll
    for (int ni = 0; ni < 4; ++ni)
#pragma unroll
      for (int e = 0; e < 4; ++e) {
        int gm = m0 + wr + mi * 16 + lg * 4 + e;     // D row = (lane>>4)*4+e  [m89-verified]
        int gn = n0 + wc + ni * 16 + l15;            // D col = lane&15
        float v = acc[mi][ni][e] + bias[gn];
        if (MODE == 0) {
          ((unsigned short*)Cout)[(size_t)gm * Ndim + gn] = f2bf(v);
        } else if (MODE == 1) {
          ((float*)Cout)[(size_t)gm * Ndim + gn] = v;
        } else {
          int b_ = gm >> 10, pos = gm & 1023;
          int h = gn >> 8, d = gn & 255;
          ((unsigned short*)Cout)[((size_t)((b_ * 8 + h) * 256 + d)) * 1024 + pos] = f2bf(v);
        }
      }
}

// ---------------- separable position bias via MFMA ----------------
// Table row: row side = k - i + 31 (row_mat[i,k]); col side = j - k + 31 (col_mat[j,l]).
__global__ __launch_bounds__(256, 4) void bias_mfma_kernel(const unsigned short* __restrict__ Q,
    const float* __restrict__ row_tab, const float* __restrict__ col_tab,
    float* __restrict__ Rb, float* __restrict__ Cb) {
  const int side = blockIdx.y >> 5;          // 0 = row, 1 = col
  const int ij = blockIdx.y & 31;            // i (row side) or j (col side)
  const int q4 = blockIdx.x;                 // row quarter
  const int tid = threadIdx.x, wv = tid >> 6, lane = tid & 63;
  const int l15 = lane & 15, lg = lane >> 4;
  const float* tab = side ? col_tab : row_tab;
  const int doff = side ? 128 : 0;
  float* outp = side ? Cb : Rb;

  // emb B-frags: eb[nf][ks] holds emb[k = nf*16+l15][d = ks*32+lg*8 ..+7]
  short8 eb[2][4];
#pragma unroll
  for (int nf = 0; nf < 2; ++nf) {
    int k = nf * 16 + l15;
    int trow = side ? (ij - k + 31) : (k - ij + 31);
    const float* tp = tab + (size_t)trow * 128 + lg * 8;
#pragma unroll
    for (int ks = 0; ks < 4; ++ks) {
      float4 f0 = *(const float4*)(tp + ks * 32);
      float4 f1 = *(const float4*)(tp + ks * 32 + 4);
      u32x4 r;
      r.x = packbf(f0.x, f0.y);
      r.y = packbf(f0.z, f0.w);
      r.z = packbf(f1.x, f1.y);
      r.w = packbf(f1.z, f1.w);
      eb[nf][ks] = *(short8*)&r;
    }
  }

  const f32x4 z = {0.f, 0.f, 0.f, 0.f};
  const int rbase = q4 * 512 + wv * 128;     // row id r = ((b*32 + jj)*8 + h)
#pragma unroll
  for (int mf = 0; mf < 8; ++mf) {
    int r = rbase + mf * 16 + l15;
    int b = r >> 8, jj = (r >> 3) & 31, h = r & 7;
    int q = side ? (jj * 32 + ij) : (ij * 32 + jj);
    const unsigned short* ap = Q + (size_t)(b * 1024 + q) * 2048 + h * 256 + doff + lg * 8;
    short8 af[4];
#pragma unroll
    for (int ks = 0; ks < 4; ++ks) af[ks] = *(const short8*)(ap + ks * 32);
    f32x4 a0 = z, a1 = z;
#pragma unroll
    for (int ks = 0; ks < 4; ++ks) {
      a0 = mfma16(af[ks], eb[0][ks], a0);
      a1 = mfma16(af[ks], eb[1][ks], a1);
    }
#pragma unroll
    for (int e = 0; e < 4; ++e) {
      int r2 = rbase + mf * 16 + lg * 4 + e;
      int b2 = r2 >> 8, jj2 = (r2 >> 3) & 31, h2 = r2 & 7;
      int q2 = side ? (jj2 * 32 + ij) : (ij * 32 + jj2);
      float* op = outp + ((size_t)((b2 * 8 + h2) * 1024 + q2)) * 32 + l15;
      op[0] = a0[e];
      op[16] = a1[e];
    }
  }
}

// ---------------- flash attention: 8-wave, 4-buffer ring, counted-vmcnt pipeline ----
// (R6 known-good: 183us, FETCH 68MB) 256 blocks x 512 thr; 256 q/block, 32 q/wave, KV=32.
__global__ __launch_bounds__(512, 2) void attn_kernel(const unsigned short* __restrict__ Q,
    const unsigned short* __restrict__ K, const unsigned short* __restrict__ Vt,
    const float* __restrict__ Rb, const float* __restrict__ Cb,
    unsigned short* __restrict__ Att) {
  __shared__ __align__(16) char KV[4][32768];      // ring: [K 16KB | V 16KB] each
  __shared__ unsigned short RbL[256 * 32];         // row-bias [qlocal][t], bf16
  const int wgid = blockIdx.x;                     // 0..255
  const int bh = (wgid & 7) * 8 + ((wgid >> 3) & 7);  // siblings (qblk) share XCD
  const int qblk = wgid >> 6;                      // 0..3
  const int b = bh >> 3, h = bh & 7;
  const int tid = threadIdx.x, wv = tid >> 6, lane = tid & 63;
  const int l15 = lane & 15, lg = lane >> 4;
  const int q0w = qblk * 256 + wv * 32;            // wave's queries: q0w + qf*16 + l15

  const unsigned short* kbase = K + (size_t)(b * 1024) * 2048 + h * 256;
  const unsigned short* vbase = Vt + (size_t)bh * 256 * 1024;

  // ---- staging: linear LDS dest, pre-swizzled global source (32KB per tile) ----
  auto stage = [&](int buf, int t) {
#pragma unroll
    for (int it = 0; it < 2; ++it) {               // K: 16KB
      int s = it * 8192 + wv * 1024 + lane * 16;
      int key = s >> 9;
      int c = ((s >> 4) & 31) ^ (key & 7);
      gll16(kbase + (size_t)(t * 32 + key) * 2048 + c * 8, &KV[buf][it * 8192 + wv * 1024]);
    }
#pragma unroll
    for (int it = 0; it < 2; ++it) {               // V: 16KB
      int s = it * 8192 + wv * 1024 + lane * 16;
      int r = s >> 9;
      int cc = ((s >> 4) & 31) ^ (r & 7);
      int d = r * 8 + (cc >> 2);
      gll16(vbase + (size_t)d * 1024 + t * 32 + (cc & 3) * 8,
            &KV[buf][16384 + it * 8192 + wv * 1024]);
    }
  };

  stage(0, 0);
  stage(1, 1);

  // prologue register loads (all drained by compiler before loop entry)
  short8 qa[2][8];
#pragma unroll
  for (int qf = 0; qf < 2; ++qf) {
    const unsigned short* qp = Q + (size_t)(b * 1024 + q0w + qf * 16 + l15) * 2048 + h * 256;
#pragma unroll
    for (int kk = 0; kk < 8; ++kk) qa[qf][kk] = *(const short8*)(qp + kk * 32 + lg * 8);
  }
  float4 cpre[2][2];
#pragma unroll
  for (int qf = 0; qf < 2; ++qf) {
    const float* cbp = Cb + ((size_t)bh * 1024 + q0w + qf * 16 + l15) * 32;
    cpre[qf][0] = *(const float4*)(cbp + lg * 4);
    cpre[qf][1] = *(const float4*)(cbp + 16 + lg * 4);
  }
  // row-bias -> LDS (bf16). 256 q x 32 t.
  {
    const float* rsrc = Rb + ((size_t)bh * 1024 + qblk * 256) * 32;
#pragma unroll
    for (int i = 0; i < 16; ++i) {
      int idx = i * 512 + tid;                     // linear over [q][t]
      RbL[idx] = f2bf(rsrc[idx]);
    }
  }
  asm volatile("s_waitcnt lgkmcnt(0)" ::: "memory");  // RbL writes visible pre-barrier

  const f32x4 z = {0.f, 0.f, 0.f, 0.f};
  f32x4 o[16][2];                                  // O^T: d = nf2*16+lg*4+e, q = qf*16+l15
#pragma unroll
  for (int nf2 = 0; nf2 < 16; ++nf2) { o[nf2][0] = z; o[nf2][1] = z; }
  float m_r[2] = {-1e30f, -1e30f}, l_r[2] = {0.f, 0.f};

  const int nfd = lg >> 1;                         // P-shuffle dest params
  const int srcA = ((lg & 1) * 2) * 16 + l15, srcB = srcA + 16;
  const unsigned short* rbl0 = &RbL[(wv * 32 + l15) * 32];
  const unsigned short* rbl1 = rbl0 + 16 * 32;

  for (int t = 0; t < 32; ++t) {
    if (t < 30) stage((t + 2) & 3, t + 2);
    // wait own current-tile loads (keep 2 stages = 8 loads in flight), then barrier
    if (t < 30)       asm volatile("s_waitcnt vmcnt(8)" ::: "memory");
    else if (t == 30) asm volatile("s_waitcnt vmcnt(4)" ::: "memory");
    else              asm volatile("s_waitcnt vmcnt(0)" ::: "memory");
    __builtin_amdgcn_s_barrier();
    asm volatile("" ::: "memory");

    const char* kb = &KV[t & 3][0];
    const char* vb = &KV[t & 3][16384];

    // ---- S^T = K @ Q^T : key = nf*16+lg*4+e, q = qf*16+l15 ----
    f32x4 s[2][2] = {{z, z}, {z, z}};              // [qf][nf]
#pragma unroll
    for (int kk = 0; kk < 8; ++kk) {
      int c0 = (kk * 4 + lg) ^ (l15 & 7);
      short8 k0 = *(const short8*)(kb + l15 * 512 + c0 * 16);
      int key1 = 16 + l15;
      int c1 = (kk * 4 + lg) ^ (key1 & 7);
      short8 k1 = *(const short8*)(kb + key1 * 512 + c1 * 16);
      s[0][0] = mfma16(k0, qa[0][kk], s[0][0]);
      s[1][0] = mfma16(k0, qa[1][kk], s[1][0]);
      s[0][1] = mfma16(k1, qa[0][kk], s[0][1]);
      s[1][1] = mfma16(k1, qa[1][kk], s[1][1]);
    }
    // ---- bias: krow = t (uniform), kcol = nf*16+lg*4+e ----
    float rb0 = bf2f(rbl0[t]), rb1 = bf2f(rbl1[t]);
#pragma unroll
    for (int nf = 0; nf < 2; ++nf)
#pragma unroll
      for (int e = 0; e < 4; ++e) {
        s[0][nf][e] += rb0 + ((const float*)&cpre[0][nf])[e];
        s[1][nf][e] += rb1 + ((const float*)&cpre[1][nf])[e];
      }
    // ---- online softmax (8 keys in-lane + xor16/32), defer-max THR=8 ----
    float tm[2];
#pragma unroll
    for (int qf = 0; qf < 2; ++qf) {
      float m2 = fmaxf(fmaxf(s[qf][0][0], s[qf][0][1]), fmaxf(s[qf][0][2], s[qf][0][3]));
#pragma unroll
      for (int e = 0; e < 4; ++e) m2 = fmaxf(m2, s[qf][1][e]);
      m2 = fmaxf(m2, __shfl_xor(m2, 16));
      m2 = fmaxf(m2, __shfl_xor(m2, 32));
      tm[qf] = m2;
    }
    if (__any((tm[0] > m_r[0] + 8.f) || (tm[1] > m_r[1] + 8.f))) {
#pragma unroll
      for (int qf = 0; qf < 2; ++qf) {
        float mn = fmaxf(m_r[qf], tm[qf]);
        float sc = __expf(m_r[qf] - mn);
        m_r[qf] = mn;
        l_r[qf] *= sc;
#pragma unroll
        for (int nf2 = 0; nf2 < 16; ++nf2)
#pragma unroll
          for (int e = 0; e < 4; ++e) o[nf2][qf][e] *= sc;
      }
    }
    short8 pb[2];
#pragma unroll
    for (int qf = 0; qf < 2; ++qf) {
      float ps = 0.f;
#pragma unroll
      for (int nf = 0; nf < 2; ++nf)
#pragma unroll
        for (int e = 0; e < 4; ++e) {
          float pv = __expf(s[qf][nf][e] - m_r[qf]);
          s[qf][nf][e] = pv;
          ps += pv;
        }
      ps += __shfl_xor(ps, 16);
      ps += __shfl_xor(ps, 32);
      l_r[qf] += ps;
      // pack + redistribute P to PV B-frag (keys lg*8..+7 for q=l15 col)
      unsigned u0 = packbf(s[qf][0][0], s[qf][0][1]);
      unsigned u1 = packbf(s[qf][0][2], s[qf][0][3]);
      unsigned u2 = packbf(s[qf][1][0], s[qf][1][1]);
      unsigned u3 = packbf(s[qf][1][2], s[qf][1][3]);
      unsigned a0 = __shfl(u0, srcA), b0 = __shfl(u2, srcA);
      unsigned a1 = __shfl(u1, srcA), b1 = __shfl(u3, srcA);
      unsigned a2 = __shfl(u0, srcB), b2 = __shfl(u2, srcB);
      unsigned a3 = __shfl(u1, srcB), b3 = __shfl(u3, srcB);
      u32x4 r4;
      r4.x = nfd ? b0 : a0;
      r4.y = nfd ? b1 : a1;
      r4.z = nfd ? b2 : a2;
      r4.w = nfd ? b3 : a3;
      pb[qf] = *(short8*)&r4;
    }
    // ---- O^T += V^T @ P ----
#pragma unroll
    for (int nf2 = 0; nf2 < 16; ++nf2) {
      int d = nf2 * 16 + l15;
      int r = d >> 3;
      int cc = ((d & 7) * 4 + lg) ^ (r & 7);
      short8 vf = *(const short8*)(vb + r * 512 + cc * 16);
      o[nf2][0] = mfma16(vf, pb[0], o[nf2][0]);
      o[nf2][1] = mfma16(vf, pb[1], o[nf2][1]);
    }
    // no trailing barrier: buffer (t+2)&3 was last read at compute(t-2),
    // which precedes barrier(t-1) in all waves' program order.
  }
  // epilogue: q = q0w+qf*16+l15, d = nf2*16+lg*4+e
#pragma unroll
  for (int qf = 0; qf < 2; ++qf) {
    unsigned short* op = Att + (size_t)(b * 1024 + q0w + qf * 16 + l15) * 2048 + h * 256;
    float inv = 1.f / l_r[qf];
#pragma unroll
    for (int nf2 = 0; nf2 < 16; ++nf2) {
      u32x2 w;
      w.x = packbf(o[nf2][qf][0] * inv, o[nf2][qf][1] * inv);
      w.y = packbf(o[nf2][qf][2] * inv, o[nf2][qf][3] * inv);
      *(u32x2*)(op + nf2 * 16 + lg * 4) = w;
    }
  }
}

// ---------------- launch ----------------
extern "C" void kernel_launch(void* const* d_in, const int* in_sizes, int n_in,
                              void* d_out, int out_size, void* d_ws, size_t ws_size,
                              hipStream_t stream) {
  (void)in_sizes; (void)n_in; (void)out_size;
  const float* x   = (const float*)d_in[0];
  const float* Kw  = (const float*)d_in[1];
  const float* Kb  = (const float*)d_in[2];
  const float* Qw  = (const float*)d_in[3];
  const float* Qb  = (const float*)d_in[4];
  const float* Vw  = (const float*)d_in[5];
  const float* Vb  = (const float*)d_in[6];
  const float* Pw  = (const float*)d_in[7];
  const float* Pb  = (const float*)d_in[8];
  const float* row_tab = (const float*)d_in[9];
  const float* col_tab = (const float*)d_in[10];
  float* out = (float*)d_out;

  char* ws = (char*)d_ws;
  size_t off = 0;
  auto alloc = [&](size_t bytes) { char* p = ws + off; off += bytes; return p; };
  unsigned short* Xb   = (unsigned short*)alloc((size_t)8192 * 256 * 2);
  unsigned short* WqT  = (unsigned short*)alloc((size_t)2048 * 256 * 2);
  unsigned short* WkT  = (unsigned short*)alloc((size_t)2048 * 256 * 2);
  unsigned short* WvT  = (unsigned short*)alloc((size_t)2048 * 256 * 2);
  unsigned short* PwT  = (unsigned short*)alloc((size_t)256 * 2048 * 2);
  unsigned short* Qg   = (unsigned short*)alloc((size_t)8192 * 2048 * 2);
  unsigned short* Kg   = (unsigned short*)alloc((size_t)8192 * 2048 * 2);
  unsigned short* VtG  = (unsigned short*)alloc((size_t)8192 * 2048 * 2);
  unsigned short* AttG = (unsigned short*)alloc((size_t)8192 * 2048 * 2);
  float* Rb = (float*)alloc((size_t)64 * 1024 * 32 * 4);
  float* Cb = (float*)alloc((size_t)64 * 1024 * 32 * 4);
  if (off > ws_size) return;  // workspace too small: bail rather than fault

  cvt_x_kernel<<<2048, 256, 0, stream>>>(x, Xb, 8192 * 256 / 4);
  transpose4_kernel<<<dim3(64, 8, 4), 256, 0, stream>>>(Qw, Kw, Vw, Pw, WqT, WkT, WvT, PwT);

  gemm128<0, 2><<<dim3(16, 64), 256, 0, stream>>>(Xb, WqT, Qb, Qg, 8192, 2048, 256);
  gemm128<0, 2><<<dim3(16, 64), 256, 0, stream>>>(Xb, WkT, Kb, Kg, 8192, 2048, 256);
  gemm128<2, 2><<<dim3(16, 64), 256, 0, stream>>>(Xb, WvT, Vb, VtG, 8192, 2048, 256);

  bias_mfma_kernel<<<dim3(4, 64), 256, 0, stream>>>(Qg, row_tab, col_tab, Rb, Cb);
  attn_kernel<<<256, 512, 0, stream>>>(Qg, Kg, VtG, Rb, Cb, AttG);
  gemm128<1, 1><<<dim3(2, 128), 256, 0, stream>>>(AttG, PwT, Pb, out, 8192, 256, 2048);
}

// Round 15
// 272.435 us; speedup vs baseline: 1.0311x; 1.0311x over previous
//
#include <hip/hip_runtime.h>

typedef __attribute__((ext_vector_type(8))) short short8;
typedef __attribute__((ext_vector_type(4))) float f32x4;
typedef __attribute__((ext_vector_type(2))) unsigned int u32x2;
typedef __attribute__((ext_vector_type(4))) unsigned int u32x4;

__device__ __forceinline__ unsigned short f2bf(float f) {
  unsigned u = __float_as_uint(f);
  u += 0x7FFF + ((u >> 16) & 1);   // RNE to bf16
  return (unsigned short)(u >> 16);
}
__device__ __forceinline__ unsigned packbf(float a, float b) {
  return (unsigned)f2bf(a) | ((unsigned)f2bf(b) << 16);
}
__device__ __forceinline__ float bf2f(unsigned short s) {
  return __uint_as_float(((unsigned)s) << 16);
}
__device__ __forceinline__ f32x4 mfma16(short8 a, short8 b, f32x4 c) {
  return __builtin_amdgcn_mfma_f32_16x16x32_bf16(a, b, c, 0, 0, 0);
}

typedef __attribute__((address_space(3))) unsigned int lds_u32;
typedef __attribute__((address_space(1))) const unsigned int glb_u32;
__device__ __forceinline__ void gll16(const void* g, void* l) {
  // dest = wave-uniform LDS base; HW adds lane*16 (m104). size literal 16.
  __builtin_amdgcn_global_load_lds((glb_u32*)g, (lds_u32*)l, 16, 0, 0);
}

// ---------------- converts ----------------
// vectorized: 4 f32 in, 4 bf16 out per thread (G13)
__global__ void cvt_x_kernel(const float* __restrict__ in, unsigned short* __restrict__ out, int n4) {
  int i = blockIdx.x * 256 + threadIdx.x;
  if (i < n4) {
    float4 v = ((const float4*)in)[i];
    u32x2 w;
    w.x = packbf(v.x, v.y);
    w.y = packbf(v.z, v.w);
    *(u32x2*)(out + i * 4) = w;
  }
}

// ---- fused coalesced transpose of all 4 weight matrices (LDS 32x32 tile) ----
__global__ void transpose4_kernel(const float* __restrict__ Qw, const float* __restrict__ Kw,
                                  const float* __restrict__ Vw, const float* __restrict__ Pw,
                                  unsigned short* __restrict__ WqT, unsigned short* __restrict__ WkT,
                                  unsigned short* __restrict__ WvT, unsigned short* __restrict__ PwT) {
  __shared__ float tile[32][33];           // +1 pad: transposed reads conflict-free
  const int z = blockIdx.z;
  const float* src;
  unsigned short* dst;
  int K, N, kt, nt;
  if (z < 3) {
    src = (z == 0) ? Qw : (z == 1) ? Kw : Vw;
    dst = (z == 0) ? WqT : (z == 1) ? WkT : WvT;
    K = 256; N = 2048;
    nt = blockIdx.x; kt = blockIdx.y;      // 64 x 8 tiles
  } else {
    src = Pw; dst = PwT;
    K = 2048; N = 256;
    kt = blockIdx.x; nt = blockIdx.y;      // 64 x 8 tiles
  }
  const int tx = threadIdx.x & 31, ty = threadIdx.x >> 5;
  const int k0 = kt * 32, n0 = nt * 32;
#pragma unroll
  for (int j = 0; j < 4; ++j)              // coalesced 128B row reads
    tile[ty + j * 8][tx] = src[(size_t)(k0 + ty + j * 8) * N + n0 + tx];
  __syncthreads();
#pragma unroll
  for (int j = 0; j < 4; ++j)              // coalesced 64B row writes, out[n][k] = in[k][n]
    dst[(size_t)(n0 + ty + j * 8) * K + k0 + tx] = f2bf(tile[tx][ty + j * 8]);
}

// ---------------- GEMM (m97-style): C[M,N] = A[M,K] @ BT[N,K]^T + bias ----------------
template<int MODE, int BMI>
__global__ __launch_bounds__(256, 2) void gemm128(const unsigned short* __restrict__ A,
    const unsigned short* __restrict__ BT, const float* __restrict__ bias,
    void* __restrict__ Cout, int Mdim, int Ndim, int Kdim) {
  constexpr int BM = 64 * BMI, MI = 2 * BMI;
  __shared__ __align__(16) short As[BM * 32];
  __shared__ __align__(16) short Bs[128 * 32];
  const int tid = threadIdx.x;
  const int wid = tid >> 6, lane = tid & 63;
  const int l15 = lane & 15, lg = lane >> 4;
  const int m0 = blockIdx.y * BM, n0 = blockIdx.x * 128;
  const int wr = (wid >> 1) * (BM / 2), wc = (wid & 1) * 64;
  const int srow = lane >> 2, schunk = (lane & 3) * 8;   // staging row/chunk per lane
  const f32x4 z = {0.f, 0.f, 0.f, 0.f};
  f32x4 acc[MI][4];
#pragma unroll
  for (int mi = 0; mi < MI; ++mi)
#pragma unroll
    for (int ni = 0; ni < 4; ++ni) acc[mi][ni] = z;

  for (int kt = 0; kt < Kdim; kt += 32) {
#pragma unroll
    for (int i = 0; i < BMI; ++i) {        // A: BM rows x 64B, BM/4 rows per wave
      int r0 = wid * (BM / 4) + i * 16;
      gll16(A + (size_t)(m0 + r0 + srow) * Kdim + kt + schunk, &As[r0 * 32]);
    }
#pragma unroll
    for (int i = 0; i < 2; ++i) {          // B: 128 rows x 64B, 32 rows per wave
      int r0 = wid * 32 + i * 16;
      gll16(BT + (size_t)(n0 + r0 + srow) * Kdim + kt + schunk, &Bs[r0 * 32]);
    }
    __syncthreads();                       // drains vmcnt (m97 pattern)
    short8 a[MI], b[4];
#pragma unroll
    for (int mi = 0; mi < MI; ++mi) a[mi] = *(const short8*)&As[(wr + mi * 16 + l15) * 32 + lg * 8];
#pragma unroll
    for (int ni = 0; ni < 4; ++ni) b[ni] = *(const short8*)&Bs[(wc + ni * 16 + l15) * 32 + lg * 8];
#pragma unroll
    for (int mi = 0; mi < MI; ++mi)
#pragma unroll
      for (int ni = 0; ni < 4; ++ni)
        acc[mi][ni] = mfma16(a[mi], b[ni], acc[mi][ni]);
    __syncthreads();
  }
#pragma unroll
  for (int mi = 0; mi < MI; ++mi)
#pragma unroll
    for (int ni = 0; ni < 4; ++ni)
#pragma unroll
      for (int e = 0; e < 4; ++e) {
        int gm = m0 + wr + mi * 16 + lg * 4 + e;     // D row = (lane>>4)*4+e  [m89-verified]
        int gn = n0 + wc + ni * 16 + l15;            // D col = lane&15
        float v = acc[mi][ni][e] + bias[gn];
        if (MODE == 0) {
          ((unsigned short*)Cout)[(size_t)gm * Ndim + gn] = f2bf(v);
        } else if (MODE == 1) {
          ((float*)Cout)[(size_t)gm * Ndim + gn] = v;
        } else {
          int b_ = gm >> 10, pos = gm & 1023;
          int h = gn >> 8, d = gn & 255;
          ((unsigned short*)Cout)[((size_t)((b_ * 8 + h) * 256 + d)) * 1024 + pos] = f2bf(v);
        }
      }
}

// ---------------- separable position bias via MFMA ----------------
// Table row: row side = k - i + 31 (row_mat[i,k]); col side = j - k + 31 (col_mat[j,l]).
__global__ __launch_bounds__(256, 4) void bias_mfma_kernel(const unsigned short* __restrict__ Q,
    const float* __restrict__ row_tab, const float* __restrict__ col_tab,
    float* __restrict__ Rb, float* __restrict__ Cb) {
  const int side = blockIdx.y >> 5;          // 0 = row, 1 = col
  const int ij = blockIdx.y & 31;            // i (row side) or j (col side)
  const int q4 = blockIdx.x;                 // row quarter
  const int tid = threadIdx.x, wv = tid >> 6, lane = tid & 63;
  const int l15 = lane & 15, lg = lane >> 4;
  const float* tab = side ? col_tab : row_tab;
  const int doff = side ? 128 : 0;
  float* outp = side ? Cb : Rb;

  // emb B-frags: eb[nf][ks] holds emb[k = nf*16+l15][d = ks*32+lg*8 ..+7]
  short8 eb[2][4];
#pragma unroll
  for (int nf = 0; nf < 2; ++nf) {
    int k = nf * 16 + l15;
    int trow = side ? (ij - k + 31) : (k - ij + 31);
    const float* tp = tab + (size_t)trow * 128 + lg * 8;
#pragma unroll
    for (int ks = 0; ks < 4; ++ks) {
      float4 f0 = *(const float4*)(tp + ks * 32);
      float4 f1 = *(const float4*)(tp + ks * 32 + 4);
      u32x4 r;
      r.x = packbf(f0.x, f0.y);
      r.y = packbf(f0.z, f0.w);
      r.z = packbf(f1.x, f1.y);
      r.w = packbf(f1.z, f1.w);
      eb[nf][ks] = *(short8*)&r;
    }
  }

  const f32x4 z = {0.f, 0.f, 0.f, 0.f};
  const int rbase = q4 * 512 + wv * 128;     // row id r = ((b*32 + jj)*8 + h)
#pragma unroll
  for (int mf = 0; mf < 8; ++mf) {
    int r = rbase + mf * 16 + l15;
    int b = r >> 8, jj = (r >> 3) & 31, h = r & 7;
    int q = side ? (jj * 32 + ij) : (ij * 32 + jj);
    const unsigned short* ap = Q + (size_t)(b * 1024 + q) * 2048 + h * 256 + doff + lg * 8;
    short8 af[4];
#pragma unroll
    for (int ks = 0; ks < 4; ++ks) af[ks] = *(const short8*)(ap + ks * 32);
    f32x4 a0 = z, a1 = z;
#pragma unroll
    for (int ks = 0; ks < 4; ++ks) {
      a0 = mfma16(af[ks], eb[0][ks], a0);
      a1 = mfma16(af[ks], eb[1][ks], a1);
    }
#pragma unroll
    for (int e = 0; e < 4; ++e) {
      int r2 = rbase + mf * 16 + lg * 4 + e;
      int b2 = r2 >> 8, jj2 = (r2 >> 3) & 31, h2 = r2 & 7;
      int q2 = side ? (jj2 * 32 + ij) : (ij * 32 + jj2);
      float* op = outp + ((size_t)((b2 * 8 + h2) * 1024 + q2)) * 32 + l15;
      op[0] = a0[e];
      op[16] = a1[e];
    }
  }
}

// ---------------- flash attention: 8-wave, 4-buffer ring, counted-vmcnt pipeline ----
// (R6 known-good: 183us, FETCH 68MB) 256 blocks x 512 thr; 256 q/block, 32 q/wave, KV=32.
__global__ __launch_bounds__(512, 2) void attn_kernel(const unsigned short* __restrict__ Q,
    const unsigned short* __restrict__ K, const unsigned short* __restrict__ Vt,
    const float* __restrict__ Rb, const float* __restrict__ Cb,
    unsigned short* __restrict__ Att) {
  __shared__ __align__(16) char KV[4][32768];      // ring: [K 16KB | V 16KB] each
  __shared__ unsigned short RbL[256 * 32];         // row-bias [qlocal][t], bf16
  const int wgid = blockIdx.x;                     // 0..255
  const int bh = (wgid & 7) * 8 + ((wgid >> 3) & 7);  // siblings (qblk) share XCD
  const int qblk = wgid >> 6;                      // 0..3
  const int b = bh >> 3, h = bh & 7;
  const int tid = threadIdx.x, wv = tid >> 6, lane = tid & 63;
  const int l15 = lane & 15, lg = lane >> 4;
  const int q0w = qblk * 256 + wv * 32;            // wave's queries: q0w + qf*16 + l15

  const unsigned short* kbase = K + (size_t)(b * 1024) * 2048 + h * 256;
  const unsigned short* vbase = Vt + (size_t)bh * 256 * 1024;

  // ---- staging: linear LDS dest, pre-swizzled global source (32KB per tile) ----
  auto stage = [&](int buf, int t) {
#pragma unroll
    for (int it = 0; it < 2; ++it) {               // K: 16KB
      int s = it * 8192 + wv * 1024 + lane * 16;
      int key = s >> 9;
      int c = ((s >> 4) & 31) ^ (key & 7);
      gll16(kbase + (size_t)(t * 32 + key) * 2048 + c * 8, &KV[buf][it * 8192 + wv * 1024]);
    }
#pragma unroll
    for (int it = 0; it < 2; ++it) {               // V: 16KB
      int s = it * 8192 + wv * 1024 + lane * 16;
      int r = s >> 9;
      int cc = ((s >> 4) & 31) ^ (r & 7);
      int d = r * 8 + (cc >> 2);
      gll16(vbase + (size_t)d * 1024 + t * 32 + (cc & 3) * 8,
            &KV[buf][16384 + it * 8192 + wv * 1024]);
    }
  };

  stage(0, 0);
  stage(1, 1);

  // prologue register loads (all drained by compiler before loop entry)
  short8 qa[2][8];
#pragma unroll
  for (int qf = 0; qf < 2; ++qf) {
    const unsigned short* qp = Q + (size_t)(b * 1024 + q0w + qf * 16 + l15) * 2048 + h * 256;
#pragma unroll
    for (int kk = 0; kk < 8; ++kk) qa[qf][kk] = *(const short8*)(qp + kk * 32 + lg * 8);
  }
  float4 cpre[2][2];
#pragma unroll
  for (int qf = 0; qf < 2; ++qf) {
    const float* cbp = Cb + ((size_t)bh * 1024 + q0w + qf * 16 + l15) * 32;
    cpre[qf][0] = *(const float4*)(cbp + lg * 4);
    cpre[qf][1] = *(const float4*)(cbp + 16 + lg * 4);
  }
  // row-bias -> LDS (bf16). 256 q x 32 t.
  {
    const float* rsrc = Rb + ((size_t)bh * 1024 + qblk * 256) * 32;
#pragma unroll
    for (int i = 0; i < 16; ++i) {
      int idx = i * 512 + tid;                     // linear over [q][t]
      RbL[idx] = f2bf(rsrc[idx]);
    }
  }
  asm volatile("s_waitcnt lgkmcnt(0)" ::: "memory");  // RbL writes visible pre-barrier

  const f32x4 z = {0.f, 0.f, 0.f, 0.f};
  f32x4 o[16][2];                                  // O^T: d = nf2*16+lg*4+e, q = qf*16+l15
#pragma unroll
  for (int nf2 = 0; nf2 < 16; ++nf2) { o[nf2][0] = z; o[nf2][1] = z; }
  float m_r[2] = {-1e30f, -1e30f}, l_r[2] = {0.f, 0.f};

  const int nfd = lg >> 1;                         // P-shuffle dest params
  const int srcA = ((lg & 1) * 2) * 16 + l15, srcB = srcA + 16;
  const unsigned short* rbl0 = &RbL[(wv * 32 + l15) * 32];
  const unsigned short* rbl1 = rbl0 + 16 * 32;

  for (int t = 0; t < 32; ++t) {
    if (t < 30) stage((t + 2) & 3, t + 2);
    // wait own current-tile loads (keep 2 stages = 8 loads in flight), then barrier
    if (t < 30)       asm volatile("s_waitcnt vmcnt(8)" ::: "memory");
    else if (t == 30) asm volatile("s_waitcnt vmcnt(4)" ::: "memory");
    else              asm volatile("s_waitcnt vmcnt(0)" ::: "memory");
    __builtin_amdgcn_s_barrier();
    asm volatile("" ::: "memory");

    const char* kb = &KV[t & 3][0];
    const char* vb = &KV[t & 3][16384];

    // ---- S^T = K @ Q^T : key = nf*16+lg*4+e, q = qf*16+l15 ----
    f32x4 s[2][2] = {{z, z}, {z, z}};              // [qf][nf]
#pragma unroll
    for (int kk = 0; kk < 8; ++kk) {
      int c0 = (kk * 4 + lg) ^ (l15 & 7);
      short8 k0 = *(const short8*)(kb + l15 * 512 + c0 * 16);
      int key1 = 16 + l15;
      int c1 = (kk * 4 + lg) ^ (key1 & 7);
      short8 k1 = *(const short8*)(kb + key1 * 512 + c1 * 16);
      s[0][0] = mfma16(k0, qa[0][kk], s[0][0]);
      s[1][0] = mfma16(k0, qa[1][kk], s[1][0]);
      s[0][1] = mfma16(k1, qa[0][kk], s[0][1]);
      s[1][1] = mfma16(k1, qa[1][kk], s[1][1]);
    }
    // ---- bias: krow = t (uniform), kcol = nf*16+lg*4+e ----
    float rb0 = bf2f(rbl0[t]), rb1 = bf2f(rbl1[t]);
#pragma unroll
    for (int nf = 0; nf < 2; ++nf)
#pragma unroll
      for (int e = 0; e < 4; ++e) {
        s[0][nf][e] += rb0 + ((const float*)&cpre[0][nf])[e];
        s[1][nf][e] += rb1 + ((const float*)&cpre[1][nf])[e];
      }
    // ---- online softmax (8 keys in-lane + xor16/32), defer-max THR=8 ----
    float tm[2];
#pragma unroll
    for (int qf = 0; qf < 2; ++qf) {
      float m2 = fmaxf(fmaxf(s[qf][0][0], s[qf][0][1]), fmaxf(s[qf][0][2], s[qf][0][3]));
#pragma unroll
      for (int e = 0; e < 4; ++e) m2 = fmaxf(m2, s[qf][1][e]);
      m2 = fmaxf(m2, __shfl_xor(m2, 16));
      m2 = fmaxf(m2, __shfl_xor(m2, 32));
      tm[qf] = m2;
    }
    if (__any((tm[0] > m_r[0] + 8.f) || (tm[1] > m_r[1] + 8.f))) {
#pragma unroll
      for (int qf = 0; qf < 2; ++qf) {
        float mn = fmaxf(m_r[qf], tm[qf]);
        float sc = __expf(m_r[qf] - mn);
        m_r[qf] = mn;
        l_r[qf] *= sc;
#pragma unroll
        for (int nf2 = 0; nf2 < 16; ++nf2)
#pragma unroll
          for (int e = 0; e < 4; ++e) o[nf2][qf][e] *= sc;
      }
    }
    short8 pb[2];
#pragma unroll
    for (int qf = 0; qf < 2; ++qf) {
      float ps = 0.f;
#pragma unroll
      for (int nf = 0; nf < 2; ++nf)
#pragma unroll
        for (int e = 0; e < 4; ++e) {
          float pv = __expf(s[qf][nf][e] - m_r[qf]);
          s[qf][nf][e] = pv;
          ps += pv;
        }
      ps += __shfl_xor(ps, 16);
      ps += __shfl_xor(ps, 32);
      l_r[qf] += ps;
      // pack + redistribute P to PV B-frag (keys lg*8..+7 for q=l15 col)
      unsigned u0 = packbf(s[qf][0][0], s[qf][0][1]);
      unsigned u1 = packbf(s[qf][0][2], s[qf][0][3]);
      unsigned u2 = packbf(s[qf][1][0], s[qf][1][1]);
      unsigned u3 = packbf(s[qf][1][2], s[qf][1][3]);
      unsigned a0 = __shfl(u0, srcA), b0 = __shfl(u2, srcA);
      unsigned a1 = __shfl(u1, srcA), b1 = __shfl(u3, srcA);
      unsigned a2 = __shfl(u0, srcB), b2 = __shfl(u2, srcB);
      unsigned a3 = __shfl(u1, srcB), b3 = __shfl(u3, srcB);
      u32x4 r4;
      r4.x = nfd ? b0 : a0;
      r4.y = nfd ? b1 : a1;
      r4.z = nfd ? b2 : a2;
      r4.w = nfd ? b3 : a3;
      pb[qf] = *(short8*)&r4;
    }
    // ---- O^T += V^T @ P ----
#pragma unroll
    for (int nf2 = 0; nf2 < 16; ++nf2) {
      int d = nf2 * 16 + l15;
      int r = d >> 3;
      int cc = ((d & 7) * 4 + lg) ^ (r & 7);
      short8 vf = *(const short8*)(vb + r * 512 + cc * 16);
      o[nf2][0] = mfma16(vf, pb[0], o[nf2][0]);
      o[nf2][1] = mfma16(vf, pb[1], o[nf2][1]);
    }
    // no trailing barrier: buffer (t+2)&3 was last read at compute(t-2),
    // which precedes barrier(t-1) in all waves' program order.
  }
  // epilogue: q = q0w+qf*16+l15, d = nf2*16+lg*4+e
#pragma unroll
  for (int qf = 0; qf < 2; ++qf) {
    unsigned short* op = Att + (size_t)(b * 1024 + q0w + qf * 16 + l15) * 2048 + h * 256;
    float inv = 1.f / l_r[qf];
#pragma unroll
    for (int nf2 = 0; nf2 < 16; ++nf2) {
      u32x2 w;
      w.x = packbf(o[nf2][qf][0] * inv, o[nf2][qf][1] * inv);
      w.y = packbf(o[nf2][qf][2] * inv, o[nf2][qf][3] * inv);
      *(u32x2*)(op + nf2 * 16 + lg * 4) = w;
    }
  }
}

// ---------------- launch ----------------
extern "C" void kernel_launch(void* const* d_in, const int* in_sizes, int n_in,
                              void* d_out, int out_size, void* d_ws, size_t ws_size,
                              hipStream_t stream) {
  (void)in_sizes; (void)n_in; (void)out_size;
  const float* x   = (const float*)d_in[0];
  const float* Kw  = (const float*)d_in[1];
  const float* Kb  = (const float*)d_in[2];
  const float* Qw  = (const float*)d_in[3];
  const float* Qb  = (const float*)d_in[4];
  const float* Vw  = (const float*)d_in[5];
  const float* Vb  = (const float*)d_in[6];
  const float* Pw  = (const float*)d_in[7];
  const float* Pb  = (const float*)d_in[8];
  const float* row_tab = (const float*)d_in[9];
  const float* col_tab = (const float*)d_in[10];
  float* out = (float*)d_out;

  char* ws = (char*)d_ws;
  size_t off = 0;
  auto alloc = [&](size_t bytes) { char* p = ws + off; off += bytes; return p; };
  unsigned short* Xb   = (unsigned short*)alloc((size_t)8192 * 256 * 2);
  unsigned short* WqT  = (unsigned short*)alloc((size_t)2048 * 256 * 2);
  unsigned short* WkT  = (unsigned short*)alloc((size_t)2048 * 256 * 2);
  unsigned short* WvT  = (unsigned short*)alloc((size_t)2048 * 256 * 2);
  unsigned short* PwT  = (unsigned short*)alloc((size_t)256 * 2048 * 2);
  unsigned short* Qg   = (unsigned short*)alloc((size_t)8192 * 2048 * 2);
  unsigned short* Kg   = (unsigned short*)alloc((size_t)8192 * 2048 * 2);
  unsigned short* VtG  = (unsigned short*)alloc((size_t)8192 * 2048 * 2);
  unsigned short* AttG = (unsigned short*)alloc((size_t)8192 * 2048 * 2);
  float* Rb = (float*)alloc((size_t)64 * 1024 * 32 * 4);
  float* Cb = (float*)alloc((size_t)64 * 1024 * 32 * 4);
  if (off > ws_size) return;  // workspace too small: bail rather than fault

  cvt_x_kernel<<<2048, 256, 0, stream>>>(x, Xb, 8192 * 256 / 4);
  transpose4_kernel<<<dim3(64, 8, 4), 256, 0, stream>>>(Qw, Kw, Vw, Pw, WqT, WkT, WvT, PwT);

  gemm128<0, 2><<<dim3(16, 64), 256, 0, stream>>>(Xb, WqT, Qb, Qg, 8192, 2048, 256);
  gemm128<0, 2><<<dim3(16, 64), 256, 0, stream>>>(Xb, WkT, Kb, Kg, 8192, 2048, 256);
  gemm128<2, 2><<<dim3(16, 64), 256, 0, stream>>>(Xb, WvT, Vb, VtG, 8192, 2048, 256);

  bias_mfma_kernel<<<dim3(4, 64), 256, 0, stream>>>(Qg, row_tab, col_tab, Rb, Cb);
  attn_kernel<<<256, 512, 0, stream>>>(Qg, Kg, VtG, Rb, Cb, AttG);
  gemm128<1, 1><<<dim3(2, 128), 256, 0, stream>>>(AttG, PwT, Pb, out, 8192, 256, 2048);
}